// Round 16
// baseline (856.829 us; speedup 1.0000x reference)
//
#include <hip/hip_runtime.h>

#define DI __device__ __forceinline__

typedef _Float16 f16_t;
typedef _Float16 f16x8 __attribute__((ext_vector_type(8)));
typedef float    f32x4 __attribute__((ext_vector_type(4)));

static_assert(sizeof(f16x8) == 16, "f16x8 must be 16B");

#define B_  16
#define C_  256
#define CH_ 128
#define N_  2048

DI f32x4 fzero(){ f32x4 z = {0.f,0.f,0.f,0.f}; return z; }
DI f16x8 ldg8(const f16_t* p){ return *(const f16x8*)p; }
DI f32x4 mfma16(f16x8 a, f16x8 b, f32x4 c){
  return __builtin_amdgcn_mfma_f32_16x16x32_f16(a, b, c, 0, 0, 0);
}
DI void split2(float v, f16_t& hi, f16_t& lo){
  hi = (f16_t)v; lo = (f16_t)(v - (float)hi);
}
// XCD-pair swizzle: blocks i≡x (mod 8) land on XCD x; give XCD x batches {2x,2x+1}
DI int swz_b(int i){ return ((i&7)<<1) | ((i>>3)&1); }

#define GLL16(src, dst) __builtin_amdgcn_global_load_lds( \
    (const __attribute__((address_space(1))) void*)(src), \
    (__attribute__((address_space(3))) void*)(dst), 16, 0, 0)

// ---------------------------------------------------------------------------
// Weight fp32 -> fp16 hi/lo split pack. Per layer: WqS[128][512] WkS[128][512]
// WvS[256][512] WtS[256][512] (cols 0..255 = hi, 256..511 = lo).
__global__ void k_wconv(const float* q1,const float* k1,const float* v1,const float* t1,
                        const float* q2,const float* k2,const float* v2,const float* t2,
                        f16_t* out){
  int i = blockIdx.x*256 + threadIdx.x;            // 0..393215
  int l = (i >= 196608) ? 1 : 0;
  int r = i - l*196608;
  const float* s; long dbase;
  if(r < 32768){ s = l? q2:q1; dbase = 0; }
  else if(r < 65536){ r -= 32768; s = l? k2:k1; dbase = 65536; }
  else if(r < 131072){ r -= 65536; s = l? v2:v1; dbase = 131072; }
  else { r -= 131072; s = l? t2:t1; dbase = 262144; }
  int o = r >> 8, c = r & 255;
  float v = s[o*256 + c];
  f16_t hi, lo; split2(v, hi, lo);
  f16_t* d = out + (long)l*393216 + dbase + (long)o*512;
  d[c] = hi; d[c+256] = lo;
}

// ---------------------------------------------------------------------------
// Transpose+split: XtS[b][n][512] = {hi(x[b][:,n]), lo}. grid (B, N/32, C/64)
__global__ void k_transpose(const float* __restrict__ X, long bstride,
                            f16_t* __restrict__ XtS){
  int b = blockIdx.x, n0 = blockIdx.y*32, c0 = blockIdx.z*64;
  __shared__ float tl[32][65];
  int t = threadIdx.x;
  int nn = t & 31, cr = t >> 5;                     // cr in 0..7
  const float* src = X + (long)b*bstride + n0 + nn;
  #pragma unroll
  for(int i=0;i<8;i++){
    int cc = cr + i*8;
    tl[nn][cc] = src[(long)(c0+cc)*N_];
  }
  __syncthreads();
  int n2 = t >> 3, cq = (t & 7)*8;
  __align__(16) f16_t hi8[8], lo8[8];
  #pragma unroll
  for(int j=0;j<8;j++) split2(tl[n2][cq+j], hi8[j], lo8[j]);
  f16_t* dst = XtS + ((long)b*N_ + n0 + n2)*512 + c0 + cq;
  *(f16x8*)dst         = *(f16x8*)hi8;
  *(f16x8*)(dst + 256) = *(f16x8*)lo8;
}

// ---------------------------------------------------------------------------
// 3-term split GEMM: out[row][col] = sum_k (Ah+Al)[row][k]*(Bh+Bl)[col][k]
// (drops Al*Bl). A,B rows are 512-wide hi|lo, K=256. 64x64 tile, 4 waves.
// 1-D grid, XCD-pair swizzle; m-tile = (r & (2^LGX-1)), n-tile = r >> LGX.
// DUAL: SPLIT_OUT cols >=128 route to a second buffer at +dualoff (Xk).
template<int LGX, int SPLIT_OUT, int BIAS, int DUAL>
__global__ __launch_bounds__(256) void k_gemm3(
    const f16_t* __restrict__ A, long sA,
    const f16_t* __restrict__ Bt, long sB,
    f16_t* __restrict__ out, int ldo, long sO,
    const float* __restrict__ bias, long dualoff)
{
  int i = blockIdx.x;
  int b = swz_b(i);
  int r = i>>4;
  int m0 = (r & ((1<<LGX)-1))*64, n0 = (r >> LGX)*64;
  int t = threadIdx.x, w = t>>6, l = t&63, lr = l&15, lg = l>>4;
  const f16_t* Ab = A + (long)b*sA + (long)(m0 + w*16 + lr)*512;
  const f16_t* Bb = Bt + (long)b*sB;
  f32x4 acc[4];
  #pragma unroll
  for(int i2=0;i2<4;i2++) acc[i2] = fzero();
  for(int k=0;k<256;k+=32){
    f16x8 ah = ldg8(Ab + k + lg*8);
    f16x8 al = ldg8(Ab + 256 + k + lg*8);
    #pragma unroll
    for(int ns=0;ns<4;ns++){
      const f16_t* brow = Bb + (long)(n0 + ns*16 + lr)*512;
      f16x8 bh = ldg8(brow + k + lg*8);
      f16x8 bl = ldg8(brow + 256 + k + lg*8);
      acc[ns] = mfma16(ah, bh, acc[ns]);
      acc[ns] = mfma16(ah, bl, acc[ns]);
      acc[ns] = mfma16(al, bh, acc[ns]);
    }
  }
  f16_t* ob = out + (long)b*sO;
  #pragma unroll
  for(int ns=0;ns<4;ns++){
    #pragma unroll
    for(int j=0;j<4;j++){
      int row = m0 + w*16 + lg*4 + j;
      int col = n0 + ns*16 + lr;
      float v = acc[ns][j];
      if(BIAS) v += bias[row];
      if(SPLIT_OUT){
        f16_t hi, lo; split2(v, hi, lo);
        f16_t* base = ob;
        if(DUAL && col >= 128) base = ob + (dualoff - 128);
        base[(long)row*ldo + col]       = hi;
        base[(long)row*ldo + col + 128] = lo;
      } else {
        ob[(long)row*ldo + col] = (f16_t)v;
      }
    }
  }
}

// ---------------------------------------------------------------------------
// Pass 1 (pipelined, 8 waves): rowoff[b][n] = rowmax + ln(sum exp). Each wave
// owns 16 n-rows (n = n0 + w*16 + lr, n0 = 128-row tile) and scans ALL m.
// K chunks (32 rows) staged via global_load_lds shared by all 8 waves,
// double-buffered, counted vmcnt(2). LDS 2x16KB. Grid 256, XCD swizzle.
// T3: 3-term split energy (layer 1; x1 error amplifies into layer-2 energies).
// T3=0: 2-term (layer 2 only; ro error ~4e-3 -> ~0.4% weight err, safe).
template<int T3>
__global__ __launch_bounds__(512) void k_rowstats(
    const f16_t* __restrict__ xqS, const f16_t* __restrict__ xkS,
    float* __restrict__ rowoff)
{
  extern __shared__ __align__(16) char smem[];     // kbuf[2] @ 0, 16384
  const int bi = blockIdx.x;
  const int b = swz_b(bi);
  const int n0 = (bi>>4)*128;
  const int t = threadIdx.x, w = t>>6, l = t&63, lr = l&15, lg = l>>4;

  const f16_t* qp = xqS + ((long)b*N_ + n0 + w*16 + lr)*256;
  f16x8 bqh[4], bql[4];
  #pragma unroll
  for(int k=0;k<4;k++){
    bqh[k] = ldg8(qp + k*32 + lg*8);
    bql[k] = ldg8(qp + 128 + k*32 + lg*8);
  }
  const f16_t* kb = xkS + (long)b*N_*256;

  const int krow_off = l>>5, kslot = l&31;
  const f16_t *ks0, *ks1;
  { int row0 = w*2 + krow_off;
    ks0 = kb + (long)row0*256 + ((kslot ^ (row0&15))*8);
    int row1 = 16 + w*2 + krow_off;
    ks1 = kb + (long)row1*256 + ((kslot ^ (row1&15))*8); }

  #define KSTAGE(buf) do { char* kd = smem + (buf)*16384;                     \
    GLL16(ks0, kd + w*1024); GLL16(ks1, kd + 8192 + w*1024); } while(0)

  float rmax = -3e38f, rsum = 0.f;
  KSTAGE(0);

  #pragma unroll 1
  for(int i=0; i<64; i++){
    const int cur = i&1, nxt = cur^1;
    if(i<63){
      ks0 += 8192; ks1 += 8192;
      KSTAGE(nxt);                                   // 2 gll ops, chunk i+1
      asm volatile("s_waitcnt vmcnt(2)" ::: "memory");
    } else {
      asm volatile("s_waitcnt vmcnt(0)" ::: "memory");
    }
    asm volatile("s_barrier" ::: "memory");
    const char* kbuf = smem + cur*16384;
    #pragma unroll
    for(int s=0;s<2;s++){
      const char* krow = kbuf + (s*16 + lr)*512;     // sw(row) = lr
      f16x8 ah[4];
      #pragma unroll
      for(int k=0;k<4;k++)
        ah[k] = *(const f16x8*)(krow + ((((4*k+lg) ^ lr))<<4));
      f32x4 a1 = fzero(), a2 = fzero(), a3 = fzero();
      #pragma unroll
      for(int k=0;k<4;k++) a1 = mfma16(ah[k],  bqh[k], a1);
      #pragma unroll
      for(int k=0;k<4;k++) a2 = mfma16(ah[k],  bql[k], a2);
      if(T3){
        #pragma unroll
        for(int k=0;k<4;k++){
          f16x8 alk = *(const f16x8*)(krow + ((16 + (((4*k+lg)) ^ lr))<<4));
          a3 = mfma16(alk, bqh[k], a3);
        }
      }
      f32x4 acc = (a1 + a2) + a3;
      float vm = fmaxf(fmaxf(acc[0],acc[1]), fmaxf(acc[2],acc[3]));
      float nm = fmaxf(rmax, vm);
      rsum = rsum*__expf(rmax-nm)
           + __expf(acc[0]-nm)+__expf(acc[1]-nm)+__expf(acc[2]-nm)+__expf(acc[3]-nm);
      rmax = nm;
    }
    asm volatile("s_barrier" ::: "memory");
  }
  #undef KSTAGE

  #pragma unroll
  for(int off=16; off<64; off<<=1){
    float om = __shfl_xor(rmax, off, 64);
    float os = __shfl_xor(rsum, off, 64);
    float nm = fmaxf(rmax, om);
    rsum = rsum*__expf(rmax-nm) + os*__expf(om-nm);
    rmax = nm;
  }
  if(lg==0) rowoff[(long)b*N_ + n0 + w*16 + lr] = rmax + __logf(rsum);
}

// ---------------------------------------------------------------------------
// Pass 2 (flash-col, pipelined): q AND V staged to LDS via global_load_lds
// (double-buffered, counted vmcnt(8)); staging source pointers hoisted and
// advanced by constant strides (no per-chunk address recompute; no setprio —
// T5 is negative on lockstep schedules). Lazy defer-max THR=8.
// LDS: q 2x16K | V 2x16K | ro 8K = 72KB dynamic. 1-D grid 512, XCD swizzle.
__global__ __launch_bounds__(256) void k_apply(
    const f16_t* __restrict__ xqS, const f16_t* __restrict__ xkS,
    const f16_t* __restrict__ xv, const float* __restrict__ rowoff,
    const float* __restrict__ X, long xbstride, f16_t* __restrict__ h0T)
{
  extern __shared__ __align__(16) char smem[];
  // layout: qbuf[2] @ 0,16384 ; vbuf[2] @ 32768,49152 ; ro_s @ 65536
  const int bi = blockIdx.x;
  const int b = swz_b(bi);
  const int m0 = (bi>>4)*64;
  const int t = threadIdx.x, w = t>>6, l = t&63, lr = l&15, lg = l>>4;
  float* ro_s = (float*)(smem + 65536);
  {
    const float* rob = rowoff + (long)b*N_;
    *(f32x4*)(ro_s + t*4)        = *(const f32x4*)(rob + t*4);
    *(f32x4*)(ro_s + t*4 + 1024) = *(const f32x4*)(rob + t*4 + 1024);
  }

  const f16_t* akp = xkS + ((long)b*N_ + m0 + w*16 + lr)*256;
  f16x8 akh[4], akl[4];
  #pragma unroll
  for(int k=0;k<4;k++){
    akh[k] = ldg8(akp + k*32 + lg*8);
    akl[k] = ldg8(akp + 128 + k*32 + lg*8);
  }

  const f16_t* xqb = xqS + (long)b*N_*256;
  const f16_t* xvb = xv + (long)b*C_*N_;
  const int qperm = ((lr>>2)*8 + (lr&3));                // + s2*4

  const int qrow_off = (l>>5), qslot = l&31;
  const int vc_off = (l>>2), vslot = l&3;

  // hoisted staging source pointers (advance by constant strides per chunk)
  const f16_t *qs0,*qs1,*qs2,*qs3,*vs0,*vs1,*vs2,*vs3;
  #define PINIT(r) { int qrow=(r*4+w)*2+qrow_off;                             \
    int qsw=(qrow&3)|(((qrow>>3)&3)<<2);                                      \
    qs##r = xqb + (long)qrow*256 + ((qslot ^ qsw)*8);                         \
    int vc=(r*4+w)*16+vc_off;                                                 \
    vs##r = xvb + (long)vc*N_ + ((vslot ^ (vc&3))*8); }
  PINIT(0) PINIT(1) PINIT(2) PINIT(3)
  #undef PINIT
  #define STAGE(buf) do {                                                     \
    char* qd = smem + (buf)*16384;                                            \
    char* vd = smem + 32768 + (buf)*16384;                                    \
    GLL16(qs0, qd + (0*4+w)*1024); GLL16(vs0, vd + (0*4+w)*1024);             \
    GLL16(qs1, qd + (1*4+w)*1024); GLL16(vs1, vd + (1*4+w)*1024);             \
    GLL16(qs2, qd + (2*4+w)*1024); GLL16(vs2, vd + (2*4+w)*1024);             \
    GLL16(qs3, qd + (3*4+w)*1024); GLL16(vs3, vd + (3*4+w)*1024); } while(0)
  #define PADV() do { qs0+=8192; qs1+=8192; qs2+=8192; qs3+=8192;             \
    vs0+=32; vs1+=32; vs2+=32; vs3+=32; } while(0)

  f32x4 y[16];
  #pragma unroll
  for(int i2=0;i2<16;i2++) y[i2] = fzero();
  float cs = 0.f, cm = -3e38f;

  __syncthreads();                 // ro_s ready
  STAGE(0);                        // chunk 0 -> buffers 0

  const int vsl = (lg ^ (lr&3)) << 4;    // per-lane V read swizzle (bytes)

  #pragma unroll 1
  for(int i=0; i<64; i++){
    const int cur = i&1, nxt = cur^1;
    const int n0 = i*32;
    if(i<63){
      PADV();
      STAGE(nxt);                                  // 8 gll ops, chunk i+1
      asm volatile("s_waitcnt vmcnt(8)" ::: "memory");
    } else {
      asm volatile("s_waitcnt vmcnt(0)" ::: "memory");
    }
    asm volatile("s_barrier" ::: "memory");           // head
    const char* qb = smem + cur*16384;
    const char* vb = smem + 32768 + cur*16384;
    // ---- energies from q LDS ----
    float g[2][4];
    #pragma unroll
    for(int s2=0;s2<2;s2++){
      const int rl = qperm + s2*4;
      const char* qrow = qb + rl*512;
      f16x8 qh[4], ql[4];
      #pragma unroll
      for(int k=0;k<4;k++){
        qh[k] = *(const f16x8*)(qrow + (((4*k + lg) ^ lr)<<4));
        ql[k] = *(const f16x8*)(qrow + 256 + (((4*k + lg) ^ lr)<<4));
      }
      f32x4 e1 = fzero(), e2 = fzero(), e3 = fzero();
      #pragma unroll
      for(int k=0;k<4;k++) e1 = mfma16(qh[k], akh[k], e1);
      #pragma unroll
      for(int k=0;k<4;k++) e2 = mfma16(ql[k], akh[k], e2);
      #pragma unroll
      for(int k=0;k<4;k++) e3 = mfma16(qh[k], akl[k], e3);
      f32x4 e = (e1 + e2) + e3;
      f32x4 ro4 = *(const f32x4*)(ro_s + n0 + lg*8 + s2*4);
      #pragma unroll
      for(int j=0;j<4;j++) g[s2][j] = e[j] - ro4[j];
    }
    // ---- lazy defer-max: per-lane test first; reduce only on rare update ----
    float vl = fmaxf(fmaxf(fmaxf(g[0][0],g[0][1]), fmaxf(g[0][2],g[0][3])),
                     fmaxf(fmaxf(g[1][0],g[1][1]), fmaxf(g[1][2],g[1][3])));
    if(__any(vl > cm + 8.f)){
      float v = vl;
      v = fmaxf(v, __shfl_xor(v, 16, 64));
      v = fmaxf(v, __shfl_xor(v, 32, 64));
      bool need = v > cm + 8.f;                 // per-column (lr) uniform
      if(need){
        float fj = __expf(cm - v);
        cm = v;
        cs *= fj;
        #pragma unroll
        for(int cf=0;cf<16;cf++){
          #pragma unroll
          for(int j2=0;j2<4;j2++) y[cf][j2] *= fj;
        }
      }
    }
    // ---- P (fp16) in-register = PV B-frag; colsum from SAME rounded values
    __align__(16) f16_t pv[8];
    #pragma unroll
    for(int s2=0;s2<2;s2++){
      #pragma unroll
      for(int j=0;j<4;j++){
        float p = __expf(g[s2][j] - cm);
        f16_t pb = (f16_t)p;
        cs += (float)pb;
        pv[s2*4+j] = pb;
      }
    }
    f16x8 pfrag = *(const f16x8*)pv;
    // ---- PV from V LDS: y[cf] covers c = cf*16 + lg*4 + j, m = lr ----
    #pragma unroll
    for(int cf=0;cf<16;cf++){
      f16x8 av = *(const f16x8*)(vb + (cf*16 + lr)*64 + vsl);
      y[cf] = mfma16(av, pfrag, y[cf]);
    }
    asm volatile("s_barrier" ::: "memory");           // tail
  }
  #undef STAGE
  #undef PADV

  // colsum across the 4 lg lane-groups (butterfly -> all lanes)
  cs += __shfl_xor(cs, 16, 64);
  cs += __shfl_xor(cs, 32, 64);
  float inv = 1.f/(1e-9f*__expf(-cm) + cs);

  // ---- two-half epilogue: x_r -> H (16KB @ vbuf[1]), h0 = X - x_r -> h0T ----
  f16_t* H = (f16_t*)(smem + 49152);
  const int mq = t&63, cq = t>>6;
  const float* Xb = X + (long)b*xbstride + m0;
  uint4* dstb = (uint4*)(h0T + ((long)b*N_ + m0)*C_);
  #pragma unroll
  for(int half=0; half<2; half++){
    #pragma unroll
    for(int cf8=0; cf8<8; cf8++){
      int cf = half*8 + cf8;
      #pragma unroll
      for(int j=0;j<4;j++){
        int cl = cf8*16 + lg*4 + j;                 // 0..127
        int m  = w*16 + lr;
        *(f16_t*)((char*)H + m*256 + ((((cl>>3) ^ (m&7))<<4) | ((cl&7)<<1)))
          = (f16_t)(y[cf][j]*inv);
      }
    }
    __syncthreads();
    #pragma unroll 4
    for(int ci=0; ci<32; ci++){
      int cl = cq*32 + ci;
      int c  = half*128 + cl;
      f16_t* hp = (f16_t*)((char*)H + mq*256 + ((((cl>>3) ^ (mq&7))<<4) | ((cl&7)<<1)));
      *hp = (f16_t)(Xb[(long)c*N_ + mq] - (float)*hp);
    }
    __syncthreads();
    {
      const uint4* src = (const uint4*)H;
      for(int i2=t;i2<1024;i2+=256){
        int row = i2>>4, slot = i2&15;
        dstb[row*32 + half*16 + slot] = src[(i2 & ~15) | (slot ^ (row&7))];
      }
    }
    __syncthreads();
  }
}

// ---------------------------------------------------------------------------
// h1[b][o][m] = Wt @ h0 + bt (2-term: Wt hi+lo), fp16 out + BN partial sums.
// 1-D grid 2048, XCD swizzle.
__global__ __launch_bounds__(256) void k_wt_bn(
    const f16_t* __restrict__ WtS, const f16_t* __restrict__ h0T,
    const float* __restrict__ bt,
    f16_t* __restrict__ h1, float* __restrict__ bnacc)
{
  int i = blockIdx.x;
  int b = swz_b(i);
  int r = i>>4;
  int o0 = (r&3)*64, m0 = (r>>2)*64;
  int t=threadIdx.x, w=t>>6, l=t&63, lr=l&15, lg=l>>4;
  const f16_t* Arow = WtS + (long)(o0 + w*16 + lr)*512;
  const f16_t* Bb = h0T + (long)b*N_*C_;
  f32x4 acc[4];
  #pragma unroll
  for(int i2=0;i2<4;i2++) acc[i2] = fzero();
  for(int k=0;k<C_;k+=32){
    f16x8 afh = ldg8(Arow + k + lg*8);
    f16x8 afl = ldg8(Arow + 256 + k + lg*8);
    #pragma unroll
    for(int ms=0;ms<4;ms++){
      f16x8 bf_ = ldg8(Bb + (long)(m0 + ms*16 + lr)*C_ + k + lg*8);
      acc[ms] = mfma16(afh, bf_, acc[ms]);
      acc[ms] = mfma16(afl, bf_, acc[ms]);
    }
  }
  float s1[4]={0.f,0.f,0.f,0.f}, s2v[4]={0.f,0.f,0.f,0.f};
  f16_t* h1b = h1 + (long)b*C_*N_;
  #pragma unroll
  for(int j=0;j<4;j++){
    int o = o0 + w*16 + lg*4 + j;
    float bias = bt[o];
    #pragma unroll
    for(int ms=0;ms<4;ms++){
      float v = acc[ms][j] + bias;
      h1b[(long)o*N_ + m0 + ms*16 + lr] = (f16_t)v;
      s1[j] += v; s2v[j] += v*v;
    }
  }
  #pragma unroll
  for(int off=1; off<16; off<<=1){
    #pragma unroll
    for(int j=0;j<4;j++){ s1[j]+=__shfl_xor(s1[j],off,64); s2v[j]+=__shfl_xor(s2v[j],off,64); }
  }
  if(lr==0){
    #pragma unroll
    for(int j=0;j<4;j++){
      int o = o0 + w*16 + lg*4 + j;
      atomicAdd(&bnacc[o], s1[j]);
      atomicAdd(&bnacc[256+o], s2v[j]);
    }
  }
}

// ---------------------------------------------------------------------------
// out = X + relu(h1*sc + sh), BN finalize inlined (reads bnacc/gamma/beta).
// Writes one 256-channel half of d_out. 8 elems/thr.
__global__ void k_out(const f16_t* __restrict__ h1, const float* __restrict__ X, long xbstride,
                      const float* __restrict__ bnacc, const float* __restrict__ gamma,
                      const float* __restrict__ beta, float* __restrict__ out, long ocoff){
  long i = (long)blockIdx.x*256 + threadIdx.x;  // 1,048,576 threads
  long e = i*8;
  int b = (int)(e >> 19);
  int rem = (int)(e & 524287);                  // c*2048 + m
  int c = rem >> 11;
  float mean = bnacc[c] * (1.f/32768.f);
  float var  = bnacc[256+c] * (1.f/32768.f) - mean*mean;
  float sc = gamma[c] * rsqrtf(var + 1e-5f);
  float sh = beta[c] - mean*sc;
  f16x8 hv = *(const f16x8*)(h1 + e);
  const float* xb = X + (long)b*xbstride + rem;
  float4 xr0 = *(const float4*)xb;
  float4 xr1 = *(const float4*)(xb + 4);
  float4 o0, o1;
  o0.x = xr0.x + fmaxf(fmaf((float)hv[0], sc, sh), 0.f);
  o0.y = xr0.y + fmaxf(fmaf((float)hv[1], sc, sh), 0.f);
  o0.z = xr0.z + fmaxf(fmaf((float)hv[2], sc, sh), 0.f);
  o0.w = xr0.w + fmaxf(fmaf((float)hv[3], sc, sh), 0.f);
  o1.x = xr1.x + fmaxf(fmaf((float)hv[4], sc, sh), 0.f);
  o1.y = xr1.y + fmaxf(fmaf((float)hv[5], sc, sh), 0.f);
  o1.z = xr1.z + fmaxf(fmaf((float)hv[6], sc, sh), 0.f);
  o1.w = xr1.w + fmaxf(fmaf((float)hv[7], sc, sh), 0.f);
  float* ob = out + (long)b*(512L*N_) + ocoff + rem;
  *(float4*)ob       = o0;
  *(float4*)(ob + 4) = o1;
}

// ---------------------------------------------------------------------------
extern "C" void kernel_launch(void* const* d_in, const int* in_sizes, int n_in,
                              void* d_out, int out_size, void* d_ws, size_t ws_size,
                              hipStream_t stream){
  (void)in_sizes; (void)n_in; (void)out_size; (void)ws_size;
  const float* x = (const float*)d_in[0];
  const float *Wf[2][4], *bv[2], *bt[2], *gm[2], *bb[2];
  for(int l=0;l<2;l++){
    int base = 1 + l*8;
    Wf[l][0]=(const float*)d_in[base+0];  // Wq
    Wf[l][1]=(const float*)d_in[base+1];  // Wk
    Wf[l][2]=(const float*)d_in[base+2];  // Wv
    bv[l]   =(const float*)d_in[base+3];
    Wf[l][3]=(const float*)d_in[base+4];  // Wt
    bt[l]   =(const float*)d_in[base+5];
    gm[l]   =(const float*)d_in[base+6];
    bb[l]   =(const float*)d_in[base+7];
  }
  char* ws = (char*)d_ws;
  size_t off = 0;
  auto alloc = [&](size_t bytes){ size_t o = off; off += (bytes + 255) & ~(size_t)255; return o; };
  size_t oXt = alloc((size_t)B_*N_*512*2);     // fp16 split x^T
  size_t oXq = alloc((size_t)B_*N_*256*2);     // fp16 split q [n][256]
  size_t oXk = alloc((size_t)B_*N_*256*2);     // fp16 split k [m][256]
  size_t oXv = alloc((size_t)B_*C_*N_*2);      // fp16 v [c][n]
  size_t oH0 = alloc((size_t)B_*N_*C_*2);      // fp16 h0^T [m][c]
  size_t oRo = alloc((size_t)B_*N_*4);         // f32 rowoff
  size_t oBn = alloc(2*512*4);                 // BN accum per layer
  size_t oW  = alloc((size_t)786432*2);        // fp16 split weights

  hipMemsetAsync(ws + oBn, 0, 2*512*4, stream);
  k_wconv<<<1536,256,0,stream>>>(Wf[0][0],Wf[0][1],Wf[0][2],Wf[0][3],
                                 Wf[1][0],Wf[1][1],Wf[1][2],Wf[1][3],
                                 (f16_t*)(ws+oW));
  float* dout = (float*)d_out;
  f16_t* H1 = (f16_t*)(ws + oXq);              // aliases Xq (dead when used)
  const long XKOFF = ((long)(oXk - oXq)) / 2;  // elements between Xq and Xk
  for(int l=0;l<2;l++){
    const float* Xl = l ? dout : x;
    long xbs = l ? 512L*N_ : 256L*N_;
    const f16_t* WqS = (const f16_t*)(ws+oW) + (size_t)l*393216;  // Wq|Wk stacked
    const f16_t* WvS = WqS + 131072;
    const f16_t* WtS = WqS + 262144;
    f16_t* XtS = (f16_t*)(ws+oXt);
    f16_t* Xq  = (f16_t*)(ws+oXq);
    f16_t* Xk  = (f16_t*)(ws+oXk);
    f16_t* Xv  = (f16_t*)(ws+oXv);
    f16_t* H0  = (f16_t*)(ws+oH0);
    float* Ro  = (float*)(ws+oRo);
    float* Bn  = (float*)(ws+oBn) + l*512;

    k_transpose<<<dim3(B_, N_/32, C_/64),256,0,stream>>>(Xl, xbs, XtS);
    // merged q+k: B = [Wq;Wk] 256 rows, 4 n-tiles -> 2048 blocks (LGX=5)
    k_gemm3<5,1,0,1><<<2048,256,0,stream>>>(XtS, (long)N_*512, WqS, 0L,
                                            Xq, 256, (long)N_*256, nullptr, XKOFF);
    k_gemm3<2,0,1,0><<<2048,256,0,stream>>>(WvS, 0L, XtS, (long)N_*512,
                                            Xv, N_, (long)C_*N_, bv[l], 0L);
    if(l==0) k_rowstats<1><<<256,512,32768,stream>>>(Xq, Xk, Ro);
    else     k_rowstats<0><<<256,512,32768,stream>>>(Xq, Xk, Ro);
    k_apply<<<512,256,73728,stream>>>(Xq, Xk, Xv, Ro, Xl, xbs, H0);
    k_wt_bn<<<2048,256,0,stream>>>(WtS, H0, bt[l], H1, Bn);
    k_out<<<4096,256,0,stream>>>(H1, Xl, xbs, Bn, gm[l], bb[l], dout, (long)l*C_*N_);
  }
}

// Round 17
// 819.645 us; speedup vs baseline: 1.0454x; 1.0454x over previous
//
#include <hip/hip_runtime.h>

#define DI __device__ __forceinline__

typedef _Float16 f16_t;
typedef _Float16 f16x8 __attribute__((ext_vector_type(8)));
typedef float    f32x4 __attribute__((ext_vector_type(4)));

static_assert(sizeof(f16x8) == 16, "f16x8 must be 16B");

#define B_  16
#define C_  256
#define CH_ 128
#define N_  2048

DI f32x4 fzero(){ f32x4 z = {0.f,0.f,0.f,0.f}; return z; }
DI f16x8 ldg8(const f16_t* p){ return *(const f16x8*)p; }
DI f32x4 mfma16(f16x8 a, f16x8 b, f32x4 c){
  return __builtin_amdgcn_mfma_f32_16x16x32_f16(a, b, c, 0, 0, 0);
}
DI void split2(float v, f16_t& hi, f16_t& lo){
  hi = (f16_t)v; lo = (f16_t)(v - (float)hi);
}
// XCD-pair swizzle: blocks i≡x (mod 8) land on XCD x; give XCD x batches {2x,2x+1}
DI int swz_b(int i){ return ((i&7)<<1) | ((i>>3)&1); }

#define GLL16(src, dst) __builtin_amdgcn_global_load_lds( \
    (const __attribute__((address_space(1))) void*)(src), \
    (__attribute__((address_space(3))) void*)(dst), 16, 0, 0)

// ---------------------------------------------------------------------------
// Weight fp32 -> fp16 hi/lo split pack. Per layer: WqS[128][512] WkS[128][512]
// WvS[256][512] WtS[256][512] (cols 0..255 = hi, 256..511 = lo).
__global__ void k_wconv(const float* q1,const float* k1,const float* v1,const float* t1,
                        const float* q2,const float* k2,const float* v2,const float* t2,
                        f16_t* out){
  int i = blockIdx.x*256 + threadIdx.x;            // 0..393215
  int l = (i >= 196608) ? 1 : 0;
  int r = i - l*196608;
  const float* s; long dbase;
  if(r < 32768){ s = l? q2:q1; dbase = 0; }
  else if(r < 65536){ r -= 32768; s = l? k2:k1; dbase = 65536; }
  else if(r < 131072){ r -= 65536; s = l? v2:v1; dbase = 131072; }
  else { r -= 131072; s = l? t2:t1; dbase = 262144; }
  int o = r >> 8, c = r & 255;
  float v = s[o*256 + c];
  f16_t hi, lo; split2(v, hi, lo);
  f16_t* d = out + (long)l*393216 + dbase + (long)o*512;
  d[c] = hi; d[c+256] = lo;
}

// ---------------------------------------------------------------------------
// Transpose+split: XtS[b][n][512] = {hi(x[b][:,n]), lo}. grid (B, N/32, C/64)
__global__ void k_transpose(const float* __restrict__ X, long bstride,
                            f16_t* __restrict__ XtS){
  int b = blockIdx.x, n0 = blockIdx.y*32, c0 = blockIdx.z*64;
  __shared__ float tl[32][65];
  int t = threadIdx.x;
  int nn = t & 31, cr = t >> 5;                     // cr in 0..7
  const float* src = X + (long)b*bstride + n0 + nn;
  #pragma unroll
  for(int i=0;i<8;i++){
    int cc = cr + i*8;
    tl[nn][cc] = src[(long)(c0+cc)*N_];
  }
  __syncthreads();
  int n2 = t >> 3, cq = (t & 7)*8;
  __align__(16) f16_t hi8[8], lo8[8];
  #pragma unroll
  for(int j=0;j<8;j++) split2(tl[n2][cq+j], hi8[j], lo8[j]);
  f16_t* dst = XtS + ((long)b*N_ + n0 + n2)*512 + c0 + cq;
  *(f16x8*)dst         = *(f16x8*)hi8;
  *(f16x8*)(dst + 256) = *(f16x8*)lo8;
}

// ---------------------------------------------------------------------------
// 3-term split GEMM: out[row][col] = sum_k (Ah+Al)[row][k]*(Bh+Bl)[col][k]
// (drops Al*Bl). A,B rows are 512-wide hi|lo, K=256. 64x64 tile, 4 waves.
// 1-D grid, XCD-pair swizzle; m-tile = (r & (2^LGX-1)), n-tile = r >> LGX.
// DUAL: SPLIT_OUT cols >=128 route to a second buffer at +dualoff (Xk).
template<int LGX, int SPLIT_OUT, int BIAS, int DUAL>
__global__ __launch_bounds__(256) void k_gemm3(
    const f16_t* __restrict__ A, long sA,
    const f16_t* __restrict__ Bt, long sB,
    f16_t* __restrict__ out, int ldo, long sO,
    const float* __restrict__ bias, long dualoff)
{
  int i = blockIdx.x;
  int b = swz_b(i);
  int r = i>>4;
  int m0 = (r & ((1<<LGX)-1))*64, n0 = (r >> LGX)*64;
  int t = threadIdx.x, w = t>>6, l = t&63, lr = l&15, lg = l>>4;
  const f16_t* Ab = A + (long)b*sA + (long)(m0 + w*16 + lr)*512;
  const f16_t* Bb = Bt + (long)b*sB;
  f32x4 acc[4];
  #pragma unroll
  for(int i2=0;i2<4;i2++) acc[i2] = fzero();
  for(int k=0;k<256;k+=32){
    f16x8 ah = ldg8(Ab + k + lg*8);
    f16x8 al = ldg8(Ab + 256 + k + lg*8);
    #pragma unroll
    for(int ns=0;ns<4;ns++){
      const f16_t* brow = Bb + (long)(n0 + ns*16 + lr)*512;
      f16x8 bh = ldg8(brow + k + lg*8);
      f16x8 bl = ldg8(brow + 256 + k + lg*8);
      acc[ns] = mfma16(ah, bh, acc[ns]);
      acc[ns] = mfma16(ah, bl, acc[ns]);
      acc[ns] = mfma16(al, bh, acc[ns]);
    }
  }
  f16_t* ob = out + (long)b*sO;
  #pragma unroll
  for(int ns=0;ns<4;ns++){
    #pragma unroll
    for(int j=0;j<4;j++){
      int row = m0 + w*16 + lg*4 + j;
      int col = n0 + ns*16 + lr;
      float v = acc[ns][j];
      if(BIAS) v += bias[row];
      if(SPLIT_OUT){
        f16_t hi, lo; split2(v, hi, lo);
        f16_t* base = ob;
        if(DUAL && col >= 128) base = ob + (dualoff - 128);
        base[(long)row*ldo + col]       = hi;
        base[(long)row*ldo + col + 128] = lo;
      } else {
        ob[(long)row*ldo + col] = (f16_t)v;
      }
    }
  }
}

// ---------------------------------------------------------------------------
// Pass 1 (pipelined, 8 waves): rowoff[b][n] = rowmax + ln(sum exp). Each wave
// owns 16 n-rows (n = n0 + w*16 + lr, n0 = 128-row tile) and scans ALL m.
// K chunks (32 rows) staged via global_load_lds shared by all 8 waves,
// double-buffered, counted vmcnt(2). LDS 2x16KB. Grid 256, XCD swizzle.
// T3: 3-term split energy (layer 1). T3=0: 2-term (layer 2; ro err ~4e-3 ok).
template<int T3>
__global__ __launch_bounds__(512) void k_rowstats(
    const f16_t* __restrict__ xqS, const f16_t* __restrict__ xkS,
    float* __restrict__ rowoff)
{
  extern __shared__ __align__(16) char smem[];     // kbuf[2] @ 0, 16384
  const int bi = blockIdx.x;
  const int b = swz_b(bi);
  const int n0 = (bi>>4)*128;
  const int t = threadIdx.x, w = t>>6, l = t&63, lr = l&15, lg = l>>4;

  const f16_t* qp = xqS + ((long)b*N_ + n0 + w*16 + lr)*256;
  f16x8 bqh[4], bql[4];
  #pragma unroll
  for(int k=0;k<4;k++){
    bqh[k] = ldg8(qp + k*32 + lg*8);
    bql[k] = ldg8(qp + 128 + k*32 + lg*8);
  }
  const f16_t* kb = xkS + (long)b*N_*256;

  const int krow_off = l>>5, kslot = l&31;
  const f16_t *ks0, *ks1;
  { int row0 = w*2 + krow_off;
    ks0 = kb + (long)row0*256 + ((kslot ^ (row0&15))*8);
    int row1 = 16 + w*2 + krow_off;
    ks1 = kb + (long)row1*256 + ((kslot ^ (row1&15))*8); }

  #define KSTAGE(buf) do { char* kd = smem + (buf)*16384;                     \
    GLL16(ks0, kd + w*1024); GLL16(ks1, kd + 8192 + w*1024); } while(0)

  float rmax = -3e38f, rsum = 0.f;
  KSTAGE(0);

  #pragma unroll 1
  for(int i=0; i<64; i++){
    const int cur = i&1, nxt = cur^1;
    if(i<63){
      ks0 += 8192; ks1 += 8192;
      KSTAGE(nxt);                                   // 2 gll ops, chunk i+1
      asm volatile("s_waitcnt vmcnt(2)" ::: "memory");
    } else {
      asm volatile("s_waitcnt vmcnt(0)" ::: "memory");
    }
    asm volatile("s_barrier" ::: "memory");
    const char* kbuf = smem + cur*16384;
    #pragma unroll
    for(int s=0;s<2;s++){
      const char* krow = kbuf + (s*16 + lr)*512;     // sw(row) = lr
      f16x8 ah[4];
      #pragma unroll
      for(int k=0;k<4;k++)
        ah[k] = *(const f16x8*)(krow + ((((4*k+lg) ^ lr))<<4));
      f32x4 a1 = fzero(), a2 = fzero(), a3 = fzero();
      #pragma unroll
      for(int k=0;k<4;k++) a1 = mfma16(ah[k],  bqh[k], a1);
      #pragma unroll
      for(int k=0;k<4;k++) a2 = mfma16(ah[k],  bql[k], a2);
      if(T3){
        #pragma unroll
        for(int k=0;k<4;k++){
          f16x8 alk = *(const f16x8*)(krow + ((16 + (((4*k+lg)) ^ lr))<<4));
          a3 = mfma16(alk, bqh[k], a3);
        }
      }
      f32x4 acc = (a1 + a2) + a3;
      float vm = fmaxf(fmaxf(acc[0],acc[1]), fmaxf(acc[2],acc[3]));
      float nm = fmaxf(rmax, vm);
      rsum = rsum*__expf(rmax-nm)
           + __expf(acc[0]-nm)+__expf(acc[1]-nm)+__expf(acc[2]-nm)+__expf(acc[3]-nm);
      rmax = nm;
    }
    asm volatile("s_barrier" ::: "memory");
  }
  #undef KSTAGE

  #pragma unroll
  for(int off=16; off<64; off<<=1){
    float om = __shfl_xor(rmax, off, 64);
    float os = __shfl_xor(rsum, off, 64);
    float nm = fmaxf(rmax, om);
    rsum = rsum*__expf(rmax-nm) + os*__expf(om-nm);
    rmax = nm;
  }
  if(lg==0) rowoff[(long)b*N_ + n0 + w*16 + lr] = rmax + __logf(rsum);
}

// ---------------------------------------------------------------------------
// Pass 2 (flash-col, pipelined, 8 waves / 128 m-rows per block): q AND V are
// m-invariant, so doubling the m-tile halves staging traffic + GLL ops +
// barriers per unit work. q/V staged to LDS (double-buffered, vmcnt(4));
// inline staging addresses (hoisting measured negative, r12/r16).
// Lazy defer-max THR=8. LDS: q 2x16K | V 2x16K | ro 8K = 72KB; H (epilogue,
// 32KB [128][128]) aliases the vbuf region. Grid 256, XCD swizzle.
__global__ __launch_bounds__(512) void k_apply(
    const f16_t* __restrict__ xqS, const f16_t* __restrict__ xkS,
    const f16_t* __restrict__ xv, const float* __restrict__ rowoff,
    const float* __restrict__ X, long xbstride, f16_t* __restrict__ h0T)
{
  extern __shared__ __align__(16) char smem[];
  // layout: qbuf[2] @ 0,16384 ; vbuf[2] @ 32768,49152 ; ro_s @ 65536
  const int bi = blockIdx.x;
  const int b = swz_b(bi);
  const int m0 = (bi>>4)*128;
  const int t = threadIdx.x, w = t>>6, l = t&63, lr = l&15, lg = l>>4;
  float* ro_s = (float*)(smem + 65536);
  {
    const float* rob = rowoff + (long)b*N_;
    *(f32x4*)(ro_s + t*4) = *(const f32x4*)(rob + t*4);   // 512 thr x 4 = 2048
  }

  const f16_t* akp = xkS + ((long)b*N_ + m0 + w*16 + lr)*256;
  f16x8 akh[4], akl[4];
  #pragma unroll
  for(int k=0;k<4;k++){
    akh[k] = ldg8(akp + k*32 + lg*8);
    akl[k] = ldg8(akp + 128 + k*32 + lg*8);
  }

  const f16_t* xqb = xqS + (long)b*N_*256;
  const f16_t* xvb = xv + (long)b*C_*N_;
  const int qperm = ((lr>>2)*8 + (lr&3));                // + s2*4

  const int qrow_off = (l>>5), qslot = l&31;
  const int vc_off = (l>>2), vslot = l&3;

  // 2 rounds x 512 threads cover 32 q-rows (16KB) and 256 V-channels (16KB)
  #define STAGE(nn, buf) do {                                                 \
    char* qd = smem + (buf)*16384;                                            \
    char* vd = smem + 32768 + (buf)*16384;                                    \
    _Pragma("unroll")                                                         \
    for(int r=0;r<2;r++){                                                     \
      int qrow = (r*8+w)*2 + qrow_off;                                        \
      int qsw  = (qrow&3) | (((qrow>>3)&3)<<2);                               \
      const f16_t* qsrc = xqb + (long)((nn) + qrow)*256 + ((qslot ^ qsw)*8);  \
      GLL16(qsrc, qd + (r*8+w)*1024);                                         \
      int vc = (r*8+w)*16 + vc_off;                                           \
      const f16_t* vsrc2 = xvb + (long)vc*N_ + (nn) + ((vslot ^ (vc&3))*8);   \
      GLL16(vsrc2, vd + (r*8+w)*1024);                                        \
    }                                                                         \
  } while(0)

  f32x4 y[16];
  #pragma unroll
  for(int i2=0;i2<16;i2++) y[i2] = fzero();
  float cs = 0.f, cm = -3e38f;

  __syncthreads();                 // ro_s ready
  STAGE(0, 0);                     // chunk 0 -> buffers 0

  const int vsl = (lg ^ (lr&3)) << 4;    // per-lane V read swizzle (bytes)

  #pragma unroll 1
  for(int i=0; i<64; i++){
    const int cur = i&1, nxt = cur^1;
    const int n0 = i*32;
    if(i<63){
      STAGE(n0+32, nxt);                           // 4 gll ops, chunk i+1
      asm volatile("s_waitcnt vmcnt(4)" ::: "memory");
    } else {
      asm volatile("s_waitcnt vmcnt(0)" ::: "memory");
    }
    asm volatile("s_barrier" ::: "memory");           // head
    const char* qb = smem + cur*16384;
    const char* vb = smem + 32768 + cur*16384;
    // ---- energies from q LDS ----
    float g[2][4];
    #pragma unroll
    for(int s2=0;s2<2;s2++){
      const int rl = qperm + s2*4;
      const char* qrow = qb + rl*512;
      f16x8 qh[4], ql[4];
      #pragma unroll
      for(int k=0;k<4;k++){
        qh[k] = *(const f16x8*)(qrow + (((4*k + lg) ^ lr)<<4));
        ql[k] = *(const f16x8*)(qrow + 256 + (((4*k + lg) ^ lr)<<4));
      }
      f32x4 e1 = fzero(), e2 = fzero(), e3 = fzero();
      #pragma unroll
      for(int k=0;k<4;k++) e1 = mfma16(qh[k], akh[k], e1);
      #pragma unroll
      for(int k=0;k<4;k++) e2 = mfma16(ql[k], akh[k], e2);
      #pragma unroll
      for(int k=0;k<4;k++) e3 = mfma16(qh[k], akl[k], e3);
      f32x4 e = (e1 + e2) + e3;
      f32x4 ro4 = *(const f32x4*)(ro_s + n0 + lg*8 + s2*4);
      #pragma unroll
      for(int j=0;j<4;j++) g[s2][j] = e[j] - ro4[j];
    }
    // ---- lazy defer-max: per-lane test first; reduce only on rare update ----
    float vl = fmaxf(fmaxf(fmaxf(g[0][0],g[0][1]), fmaxf(g[0][2],g[0][3])),
                     fmaxf(fmaxf(g[1][0],g[1][1]), fmaxf(g[1][2],g[1][3])));
    if(__any(vl > cm + 8.f)){
      float v = vl;
      v = fmaxf(v, __shfl_xor(v, 16, 64));
      v = fmaxf(v, __shfl_xor(v, 32, 64));
      bool need = v > cm + 8.f;                 // per-column (lr) uniform
      if(need){
        float fj = __expf(cm - v);
        cm = v;
        cs *= fj;
        #pragma unroll
        for(int cf=0;cf<16;cf++){
          #pragma unroll
          for(int j2=0;j2<4;j2++) y[cf][j2] *= fj;
        }
      }
    }
    // ---- P (fp16) in-register = PV B-frag; colsum from SAME rounded values
    __align__(16) f16_t pv[8];
    #pragma unroll
    for(int s2=0;s2<2;s2++){
      #pragma unroll
      for(int j=0;j<4;j++){
        float p = __expf(g[s2][j] - cm);
        f16_t pb = (f16_t)p;
        cs += (float)pb;
        pv[s2*4+j] = pb;
      }
    }
    f16x8 pfrag = *(const f16x8*)pv;
    // ---- PV from V LDS: y[cf] covers c = cf*16 + lg*4 + j, m = w*16+lr ----
    #pragma unroll
    for(int cf=0;cf<16;cf++){
      f16x8 av = *(const f16x8*)(vb + (cf*16 + lr)*64 + vsl);
      y[cf] = mfma16(av, pfrag, y[cf]);
    }
    asm volatile("s_barrier" ::: "memory");           // tail
  }
  #undef STAGE

  // colsum across the 4 lg lane-groups (butterfly -> all lanes)
  cs += __shfl_xor(cs, 16, 64);
  cs += __shfl_xor(cs, 32, 64);
  float inv = 1.f/(1e-9f*__expf(-cm) + cs);

  // ---- two-half epilogue: x_r -> H (32KB [128 m][128 c] @ vbuf region),
  //      h0 = X - x_r -> h0T ----
  f16_t* H = (f16_t*)(smem + 32768);
  const int mq = t&127, cq = t>>7;
  const float* Xb = X + (long)b*xbstride + m0;
  uint4* dstb = (uint4*)(h0T + ((long)b*N_ + m0)*C_);
  #pragma unroll
  for(int half=0; half<2; half++){
    #pragma unroll
    for(int cf8=0; cf8<8; cf8++){
      int cf = half*8 + cf8;
      #pragma unroll
      for(int j=0;j<4;j++){
        int cl = cf8*16 + lg*4 + j;                 // 0..127
        int m  = w*16 + lr;                         // 0..127
        *(f16_t*)((char*)H + m*256 + ((((cl>>3) ^ (m&7))<<4) | ((cl&7)<<1)))
          = (f16_t)(y[cf][j]*inv);
      }
    }
    __syncthreads();
    #pragma unroll 4
    for(int ci=0; ci<32; ci++){
      int cl = cq*32 + ci;
      int c  = half*128 + cl;
      f16_t* hp = (f16_t*)((char*)H + mq*256 + ((((cl>>3) ^ (mq&7))<<4) | ((cl&7)<<1)));
      *hp = (f16_t)(Xb[(long)c*N_ + mq] - (float)*hp);
    }
    __syncthreads();
    {
      const uint4* src = (const uint4*)H;
      for(int i2=t;i2<2048;i2+=512){
        int row = i2>>4, slot = i2&15;              // row 0..127
        dstb[row*32 + half*16 + slot] = src[(i2 & ~15) | (slot ^ (row&7))];
      }
    }
    __syncthreads();
  }
}

// ---------------------------------------------------------------------------
// h1[b][o][m] = Wt @ h0 + bt (2-term: Wt hi+lo), fp16 out + BN partial sums.
// 1-D grid 2048, XCD swizzle.
__global__ __launch_bounds__(256) void k_wt_bn(
    const f16_t* __restrict__ WtS, const f16_t* __restrict__ h0T,
    const float* __restrict__ bt,
    f16_t* __restrict__ h1, float* __restrict__ bnacc)
{
  int i = blockIdx.x;
  int b = swz_b(i);
  int r = i>>4;
  int o0 = (r&3)*64, m0 = (r>>2)*64;
  int t=threadIdx.x, w=t>>6, l=t&63, lr=l&15, lg=l>>4;
  const f16_t* Arow = WtS + (long)(o0 + w*16 + lr)*512;
  const f16_t* Bb = h0T + (long)b*N_*C_;
  f32x4 acc[4];
  #pragma unroll
  for(int i2=0;i2<4;i2++) acc[i2] = fzero();
  for(int k=0;k<C_;k+=32){
    f16x8 afh = ldg8(Arow + k + lg*8);
    f16x8 afl = ldg8(Arow + 256 + k + lg*8);
    #pragma unroll
    for(int ms=0;ms<4;ms++){
      f16x8 bf_ = ldg8(Bb + (long)(m0 + ms*16 + lr)*C_ + k + lg*8);
      acc[ms] = mfma16(afh, bf_, acc[ms]);
      acc[ms] = mfma16(afl, bf_, acc[ms]);
    }
  }
  float s1[4]={0.f,0.f,0.f,0.f}, s2v[4]={0.f,0.f,0.f,0.f};
  f16_t* h1b = h1 + (long)b*C_*N_;
  #pragma unroll
  for(int j=0;j<4;j++){
    int o = o0 + w*16 + lg*4 + j;
    float bias = bt[o];
    #pragma unroll
    for(int ms=0;ms<4;ms++){
      float v = acc[ms][j] + bias;
      h1b[(long)o*N_ + m0 + ms*16 + lr] = (f16_t)v;
      s1[j] += v; s2v[j] += v*v;
    }
  }
  #pragma unroll
  for(int off=1; off<16; off<<=1){
    #pragma unroll
    for(int j=0;j<4;j++){ s1[j]+=__shfl_xor(s1[j],off,64); s2v[j]+=__shfl_xor(s2v[j],off,64); }
  }
  if(lr==0){
    #pragma unroll
    for(int j=0;j<4;j++){
      int o = o0 + w*16 + lg*4 + j;
      atomicAdd(&bnacc[o], s1[j]);
      atomicAdd(&bnacc[256+o], s2v[j]);
    }
  }
}

// ---------------------------------------------------------------------------
// out = X + relu(h1*sc + sh), BN finalize inlined (reads bnacc/gamma/beta).
// Writes one 256-channel half of d_out. 8 elems/thr.
__global__ void k_out(const f16_t* __restrict__ h1, const float* __restrict__ X, long xbstride,
                      const float* __restrict__ bnacc, const float* __restrict__ gamma,
                      const float* __restrict__ beta, float* __restrict__ out, long ocoff){
  long i = (long)blockIdx.x*256 + threadIdx.x;  // 1,048,576 threads
  long e = i*8;
  int b = (int)(e >> 19);
  int rem = (int)(e & 524287);                  // c*2048 + m
  int c = rem >> 11;
  float mean = bnacc[c] * (1.f/32768.f);
  float var  = bnacc[256+c] * (1.f/32768.f) - mean*mean;
  float sc = gamma[c] * rsqrtf(var + 1e-5f);
  float sh = beta[c] - mean*sc;
  f16x8 hv = *(const f16x8*)(h1 + e);
  const float* xb = X + (long)b*xbstride + rem;
  float4 xr0 = *(const float4*)xb;
  float4 xr1 = *(const float4*)(xb + 4);
  float4 o0, o1;
  o0.x = xr0.x + fmaxf(fmaf((float)hv[0], sc, sh), 0.f);
  o0.y = xr0.y + fmaxf(fmaf((float)hv[1], sc, sh), 0.f);
  o0.z = xr0.z + fmaxf(fmaf((float)hv[2], sc, sh), 0.f);
  o0.w = xr0.w + fmaxf(fmaf((float)hv[3], sc, sh), 0.f);
  o1.x = xr1.x + fmaxf(fmaf((float)hv[4], sc, sh), 0.f);
  o1.y = xr1.y + fmaxf(fmaf((float)hv[5], sc, sh), 0.f);
  o1.z = xr1.z + fmaxf(fmaf((float)hv[6], sc, sh), 0.f);
  o1.w = xr1.w + fmaxf(fmaf((float)hv[7], sc, sh), 0.f);
  float* ob = out + (long)b*(512L*N_) + ocoff + rem;
  *(float4*)ob       = o0;
  *(float4*)(ob + 4) = o1;
}

// ---------------------------------------------------------------------------
extern "C" void kernel_launch(void* const* d_in, const int* in_sizes, int n_in,
                              void* d_out, int out_size, void* d_ws, size_t ws_size,
                              hipStream_t stream){
  (void)in_sizes; (void)n_in; (void)out_size; (void)ws_size;
  const float* x = (const float*)d_in[0];
  const float *Wf[2][4], *bv[2], *bt[2], *gm[2], *bb[2];
  for(int l=0;l<2;l++){
    int base = 1 + l*8;
    Wf[l][0]=(const float*)d_in[base+0];  // Wq
    Wf[l][1]=(const float*)d_in[base+1];  // Wk
    Wf[l][2]=(const float*)d_in[base+2];  // Wv
    bv[l]   =(const float*)d_in[base+3];
    Wf[l][3]=(const float*)d_in[base+4];  // Wt
    bt[l]   =(const float*)d_in[base+5];
    gm[l]   =(const float*)d_in[base+6];
    bb[l]   =(const float*)d_in[base+7];
  }
  char* ws = (char*)d_ws;
  size_t off = 0;
  auto alloc = [&](size_t bytes){ size_t o = off; off += (bytes + 255) & ~(size_t)255; return o; };
  size_t oXt = alloc((size_t)B_*N_*512*2);     // fp16 split x^T
  size_t oXq = alloc((size_t)B_*N_*256*2);     // fp16 split q [n][256]
  size_t oXk = alloc((size_t)B_*N_*256*2);     // fp16 split k [m][256]
  size_t oXv = alloc((size_t)B_*C_*N_*2);      // fp16 v [c][n]
  size_t oH0 = alloc((size_t)B_*N_*C_*2);      // fp16 h0^T [m][c]
  size_t oRo = alloc((size_t)B_*N_*4);         // f32 rowoff
  size_t oBn = alloc(2*512*4);                 // BN accum per layer
  size_t oW  = alloc((size_t)786432*2);        // fp16 split weights

  hipMemsetAsync(ws + oBn, 0, 2*512*4, stream);
  k_wconv<<<1536,256,0,stream>>>(Wf[0][0],Wf[0][1],Wf[0][2],Wf[0][3],
                                 Wf[1][0],Wf[1][1],Wf[1][2],Wf[1][3],
                                 (f16_t*)(ws+oW));
  float* dout = (float*)d_out;
  f16_t* H1 = (f16_t*)(ws + oXq);              // aliases Xq (dead when used)
  const long XKOFF = ((long)(oXk - oXq)) / 2;  // elements between Xq and Xk
  for(int l=0;l<2;l++){
    const float* Xl = l ? dout : x;
    long xbs = l ? 512L*N_ : 256L*N_;
    const f16_t* WqS = (const f16_t*)(ws+oW) + (size_t)l*393216;  // Wq|Wk stacked
    const f16_t* WvS = WqS + 131072;
    const f16_t* WtS = WqS + 262144;
    f16_t* XtS = (f16_t*)(ws+oXt);
    f16_t* Xq  = (f16_t*)(ws+oXq);
    f16_t* Xk  = (f16_t*)(ws+oXk);
    f16_t* Xv  = (f16_t*)(ws+oXv);
    f16_t* H0  = (f16_t*)(ws+oH0);
    float* Ro  = (float*)(ws+oRo);
    float* Bn  = (float*)(ws+oBn) + l*512;

    k_transpose<<<dim3(B_, N_/32, C_/64),256,0,stream>>>(Xl, xbs, XtS);
    // merged q+k: B = [Wq;Wk] 256 rows, 4 n-tiles -> 2048 blocks (LGX=5)
    k_gemm3<5,1,0,1><<<2048,256,0,stream>>>(XtS, (long)N_*512, WqS, 0L,
                                            Xq, 256, (long)N_*256, nullptr, XKOFF);
    k_gemm3<2,0,1,0><<<2048,256,0,stream>>>(WvS, 0L, XtS, (long)N_*512,
                                            Xv, N_, (long)C_*N_, bv[l], 0L);
    if(l==0) k_rowstats<1><<<256,512,32768,stream>>>(Xq, Xk, Ro);
    else     k_rowstats<0><<<256,512,32768,stream>>>(Xq, Xk, Ro);
    k_apply<<<256,512,73728,stream>>>(Xq, Xk, Xv, Ro, Xl, xbs, H0);
    k_wt_bn<<<2048,256,0,stream>>>(WtS, H0, bt[l], H1, Bn);
    k_out<<<4096,256,0,stream>>>(H1, Xl, xbs, Bn, gm[l], bb[l], dout, (long)l*C_*N_);
  }
}